// Round 3
// baseline (945.019 us; speedup 1.0000x reference)
//
#include <hip/hip_runtime.h>
#include <hip/hip_bf16.h>

typedef unsigned short u16;
typedef short bf16x8 __attribute__((ext_vector_type(8)));
typedef float f32x4 __attribute__((ext_vector_type(4)));

#define NEG_BIG (-1e30f)
#define LOG2E 1.44269504f

__device__ __forceinline__ u16 f2bf(float f) {
    union { float f; unsigned int u; } x; x.f = f;
    unsigned int r = x.u + 0x7fffu + ((x.u >> 16) & 1u);
    return (u16)(r >> 16);
}

__device__ __forceinline__ float scrub(float f) {   // NaN/inf -> 0 (bit test, fast-math safe)
    union { float f; unsigned int u; } x; x.f = f;
    return (((x.u >> 23) & 0xFFu) == 0xFFu) ? 0.0f : f;
}

// Detect whether a buffer holds fp32 (true) or bf16 (false).
// Even-index u16s of an fp32 array are mantissa low-halves: ~47% have bf16
// exponent >= 135. Real bf16 data here (|v| < 8) never does.
__device__ __forceinline__ bool probe_f32(const void* p) {
    const u16* q = (const u16*)p;
    int hits = 0;
#pragma unroll
    for (int i = 0; i < 64; ++i) {
        int e = (q[2 * i] >> 7) & 0xFF;
        hits += (e >= 135) ? 1 : 0;
    }
    return hits > 6;
}

__device__ __forceinline__ bf16x8 cvt8(const float* p) {
    float4 a = *(const float4*)p;
    float4 b = *(const float4*)(p + 4);
    bf16x8 r;
    r[0] = (short)f2bf(a.x); r[1] = (short)f2bf(a.y);
    r[2] = (short)f2bf(a.z); r[3] = (short)f2bf(a.w);
    r[4] = (short)f2bf(b.x); r[5] = (short)f2bf(b.y);
    r[6] = (short)f2bf(b.z); r[7] = (short)f2bf(b.w);
    return r;
}

// C[M][N] = A[M][K] @ Bt[N][K]^T, bf16 MFMA, fp32 accumulate.
// A/Bt may be fp32 or bf16 (probed on device). C: c_mode==0 -> bf16 (internal),
// c_mode==1 -> format follows probe(Bt) (final output).
__global__ __launch_bounds__(256) void gemm_nt(const void* __restrict__ A_,
                                               const void* __restrict__ Bt_,
                                               void* __restrict__ C_,
                                               int M, int N, int K, int c_mode) {
    const bool af = probe_f32(A_);
    const bool bf = probe_f32(Bt_);
    const bool cf = (c_mode == 1) ? bf : false;

    __shared__ u16 As[128][72];
    __shared__ u16 Bs[128][72];
    const int t = threadIdx.x;
    const int wave = t >> 6, lane = t & 63;
    const int wm = (wave >> 1) * 64, wn = (wave & 1) * 64;
    const int lhi = lane >> 4, llo = lane & 15;
    const int m0 = blockIdx.y * 128, n0 = blockIdx.x * 128;
    const int lr = t >> 3;
    const int lc = (t & 7) * 8;

    f32x4 acc[4][4] = {};

    for (int k0 = 0; k0 < K; k0 += 64) {
#pragma unroll
        for (int i = 0; i < 4; ++i) {
            int r = lr + 32 * i;
            bf16x8 av, bv;
            if (af) av = cvt8((const float*)A_ + (size_t)(m0 + r) * K + k0 + lc);
            else    av = *(const bf16x8*)((const u16*)A_ + (size_t)(m0 + r) * K + k0 + lc);
            if (bf) bv = cvt8((const float*)Bt_ + (size_t)(n0 + r) * K + k0 + lc);
            else    bv = *(const bf16x8*)((const u16*)Bt_ + (size_t)(n0 + r) * K + k0 + lc);
            *(bf16x8*)(&As[r][lc]) = av;
            *(bf16x8*)(&Bs[r][lc]) = bv;
        }
        __syncthreads();
#pragma unroll
        for (int ks = 0; ks < 2; ++ks) {
            const int kb = ks * 32 + lhi * 8;
            bf16x8 afr[4], bfr[4];
#pragma unroll
            for (int mi = 0; mi < 4; ++mi)
                afr[mi] = *(const bf16x8*)(&As[wm + mi * 16 + llo][kb]);
#pragma unroll
            for (int ni = 0; ni < 4; ++ni)
                bfr[ni] = *(const bf16x8*)(&Bs[wn + ni * 16 + llo][kb]);
#pragma unroll
            for (int mi = 0; mi < 4; ++mi)
#pragma unroll
                for (int ni = 0; ni < 4; ++ni)
                    acc[mi][ni] = __builtin_amdgcn_mfma_f32_16x16x32_bf16(
                        afr[mi], bfr[ni], acc[mi][ni], 0, 0, 0);
        }
        __syncthreads();
    }

#pragma unroll
    for (int mi = 0; mi < 4; ++mi)
#pragma unroll
        for (int ni = 0; ni < 4; ++ni)
#pragma unroll
            for (int r = 0; r < 4; ++r) {
                int row = m0 + wm + mi * 16 + lhi * 4 + r;
                int col = n0 + wn + ni * 16 + llo;
                float v = scrub(acc[mi][ni][r]);
                if (cf) ((float*)C_)[(size_t)row * N + col] = v;
                else    ((u16*)C_)[(size_t)row * N + col] = f2bf(v);
            }
}

// Flash-style GQA attention. All tensors internal bf16. fp32 softmax, no infinities.
__global__ __launch_bounds__(256) void attn(const u16* __restrict__ Qb,
                                            const u16* __restrict__ Kb,
                                            const u16* __restrict__ Vb,
                                            u16* __restrict__ Ctx) {
    __shared__ u16 Qs[64][72];
    __shared__ u16 Ks[64][72];
    __shared__ u16 Vts[64][72];   // transposed: [hd][seq]
    __shared__ u16 Ps[64][72];
    const int qt = blockIdx.x;
    const int bh = blockIdx.y;
    const int b = bh >> 5, h = bh & 31, g = h >> 2;
    const int t = threadIdx.x, wave = t >> 6, lane = t & 63;
    const int lhi = lane >> 4, llo = lane & 15;
    const int lr = t >> 3, lc = (t & 7) * 8;

    const u16* Qp = Qb + (size_t)b * 2048 * 2048 + (size_t)h * 64;
    const u16* Kp = Kb + (size_t)b * 2048 * 512 + (size_t)g * 64;
    const u16* Vp = Vb + (size_t)b * 2048 * 512 + (size_t)g * 64;

#pragma unroll
    for (int i = 0; i < 2; ++i) {
        int r = lr + 32 * i;
        *(bf16x8*)(&Qs[r][lc]) =
            *(const bf16x8*)(Qp + (size_t)(qt * 64 + r) * 2048 + lc);
    }

    f32x4 of[4] = {};
    float mrow[4], lsum[4];
#pragma unroll
    for (int r = 0; r < 4; ++r) { mrow[r] = NEG_BIG; lsum[r] = 0.f; }

    for (int kt = 0; kt <= qt; ++kt) {
        __syncthreads();
#pragma unroll
        for (int i = 0; i < 2; ++i) {
            int r = lr + 32 * i;
            *(bf16x8*)(&Ks[r][lc]) =
                *(const bf16x8*)(Kp + (size_t)(kt * 64 + r) * 512 + lc);
            bf16x8 vv = *(const bf16x8*)(Vp + (size_t)(kt * 64 + r) * 512 + lc);
#pragma unroll
            for (int e = 0; e < 8; ++e) Vts[lc + e][r] = (u16)vv[e];
        }
        __syncthreads();

        f32x4 sf[4] = {};
#pragma unroll
        for (int ks = 0; ks < 2; ++ks) {
            const int kb = ks * 32 + lhi * 8;
            bf16x8 aq = *(const bf16x8*)(&Qs[wave * 16 + llo][kb]);
#pragma unroll
            for (int nb = 0; nb < 4; ++nb) {
                bf16x8 bk = *(const bf16x8*)(&Ks[nb * 16 + llo][kb]);
                sf[nb] = __builtin_amdgcn_mfma_f32_16x16x32_bf16(aq, bk, sf[nb], 0, 0, 0);
            }
        }

        const bool diag = (kt == qt);
        float sv[4][4], rmax[4];
#pragma unroll
        for (int r = 0; r < 4; ++r) rmax[r] = NEG_BIG;
#pragma unroll
        for (int nb = 0; nb < 4; ++nb)
#pragma unroll
            for (int r = 0; r < 4; ++r) {
                float v = scrub(sf[nb][r]) * 0.125f;
                if (diag) {
                    int qrow = wave * 16 + lhi * 4 + r;
                    int kcol = nb * 16 + llo;
                    if (kcol > qrow) v = NEG_BIG;
                }
                sv[nb][r] = v;
                rmax[r] = fmaxf(rmax[r], v);
            }
#pragma unroll
        for (int m = 1; m < 16; m <<= 1)
#pragma unroll
            for (int r = 0; r < 4; ++r)
                rmax[r] = fmaxf(rmax[r], __shfl_xor(rmax[r], m, 64));

        float alpha[4];
#pragma unroll
        for (int r = 0; r < 4; ++r) {
            float mn = fmaxf(mrow[r], rmax[r]);
            alpha[r] = exp2f((mrow[r] - mn) * LOG2E);
            mrow[r] = mn;
        }
        float rsum[4] = {0.f, 0.f, 0.f, 0.f};
#pragma unroll
        for (int nb = 0; nb < 4; ++nb)
#pragma unroll
            for (int r = 0; r < 4; ++r) {
                float p = exp2f((sv[nb][r] - mrow[r]) * LOG2E);
                rsum[r] += p;
                Ps[wave * 16 + lhi * 4 + r][nb * 16 + llo] = f2bf(p);
            }
#pragma unroll
        for (int m = 1; m < 16; m <<= 1)
#pragma unroll
            for (int r = 0; r < 4; ++r) rsum[r] += __shfl_xor(rsum[r], m, 64);
#pragma unroll
        for (int r = 0; r < 4; ++r) lsum[r] = lsum[r] * alpha[r] + rsum[r];
#pragma unroll
        for (int hb = 0; hb < 4; ++hb)
#pragma unroll
            for (int r = 0; r < 4; ++r) of[hb][r] *= alpha[r];

        __syncthreads();   // P fully written before any lane reads it

#pragma unroll
        for (int ks = 0; ks < 2; ++ks) {
            const int kb = ks * 32 + lhi * 8;
            bf16x8 ap = *(const bf16x8*)(&Ps[wave * 16 + llo][kb]);
#pragma unroll
            for (int hb = 0; hb < 4; ++hb) {
                bf16x8 bv = *(const bf16x8*)(&Vts[hb * 16 + llo][kb]);
                of[hb] = __builtin_amdgcn_mfma_f32_16x16x32_bf16(ap, bv, of[hb], 0, 0, 0);
            }
        }
    }

    u16* Cp = Ctx + (size_t)b * 2048 * 2048 + (size_t)h * 64;
#pragma unroll
    for (int hb = 0; hb < 4; ++hb)
#pragma unroll
        for (int r = 0; r < 4; ++r) {
            int row = qt * 64 + wave * 16 + lhi * 4 + r;
            int col = hb * 16 + llo;
            float inv = 1.0f / lsum[r];
            Cp[(size_t)row * 2048 + col] = f2bf(scrub(of[hb][r] * inv));
        }
}

extern "C" void kernel_launch(void* const* d_in, const int* in_sizes, int n_in,
                              void* d_out, int out_size, void* d_ws, size_t ws_size,
                              hipStream_t stream) {
    const void* x  = d_in[0];   // [2,2048,2048]  fp32 or bf16 (device-probed)
    const void* Wq = d_in[1];   // [2048,2048]
    const void* Wk = d_in[2];   // [512,2048]
    const void* Wv = d_in[3];   // [512,2048]
    const void* Wo = d_in[4];   // [2048,2048]

    // Q staged as bf16 in d_out (>=16MB in either dtype; dead before final GEMM).
    // ws: K 4MB | V 4MB | Ctx 16MB = 24MB.
    u16* Q   = (u16*)d_out;
    u16* K   = (u16*)d_ws;
    u16* V   = K + (size_t)2 * 1024 * 1024;
    u16* Ctx = V + (size_t)2 * 1024 * 1024;

    const int M = 4096, D = 2048, KV = 512;

    gemm_nt<<<dim3(D / 128, M / 128), 256, 0, stream>>>(x, Wq, Q, M, D, D, 0);
    gemm_nt<<<dim3(KV / 128, M / 128), 256, 0, stream>>>(x, Wk, K, M, KV, D, 0);
    gemm_nt<<<dim3(KV / 128, M / 128), 256, 0, stream>>>(x, Wv, V, M, KV, D, 0);
    attn<<<dim3(32, 64), 256, 0, stream>>>(Q, K, V, Ctx);
    gemm_nt<<<dim3(D / 128, M / 128), 256, 0, stream>>>(Ctx, Wo, d_out, M, D, D, 1);
}

// Round 4
// 586.959 us; speedup vs baseline: 1.6100x; 1.6100x over previous
//
#include <hip/hip_runtime.h>
#include <hip/hip_bf16.h>

typedef unsigned short u16;
typedef short bf16x8 __attribute__((ext_vector_type(8)));
typedef float f32x4 __attribute__((ext_vector_type(4)));

#define NEG_BIG (-1e30f)
#define LOG2E 1.44269504f

__device__ __forceinline__ u16 f2bf(float f) {
    union { float f; unsigned int u; } x; x.f = f;
    unsigned int r = x.u + 0x7fffu + ((x.u >> 16) & 1u);
    return (u16)(r >> 16);
}

// async global->LDS, 16B per lane; LDS dest = wave-uniform base + lane*16
__device__ __forceinline__ void dma16(const u16* g, const u16* lds) {
    __builtin_amdgcn_global_load_lds(
        (const __attribute__((address_space(1))) unsigned int*)g,
        (__attribute__((address_space(3))) unsigned int*)lds, 16, 0, 0);
}

// fragment read from XOR-swizzled LDS tile: slot(row, kb8) = row*8 + (kb8 ^ (row&7))
__device__ __forceinline__ bf16x8 sfrag(const u16* lds, int row, int kb8) {
    int slot = row * 8 + (kb8 ^ (row & 7));
    return *(const bf16x8*)(lds + slot * 8);
}

// ---------------- fp32 -> bf16 bulk convert ----------------
__global__ __launch_bounds__(256) void cvt(const float* __restrict__ s,
                                           u16* __restrict__ d, int n8) {
    int i = blockIdx.x * 256 + threadIdx.x;
    if (i >= n8) return;
    const float* p = s + (size_t)i * 8;
    float4 a = *(const float4*)p;
    float4 b = *(const float4*)(p + 4);
    bf16x8 r;
    r[0] = (short)f2bf(a.x); r[1] = (short)f2bf(a.y);
    r[2] = (short)f2bf(a.z); r[3] = (short)f2bf(a.w);
    r[4] = (short)f2bf(b.x); r[5] = (short)f2bf(b.y);
    r[6] = (short)f2bf(b.z); r[7] = (short)f2bf(b.w);
    *(bf16x8*)(d + (size_t)i * 8) = r;
}

// ---------------- bf16 GEMM, m97-style: C = A @ Bt^T ----------------
// epi 0: C bf16 ; epi 1: C fp32
__global__ __launch_bounds__(256) void gemm_bt(const u16* __restrict__ A,
                                               const u16* __restrict__ Bt,
                                               void* __restrict__ C,
                                               int M, int N, int K, int epi) {
    __shared__ u16 As[8192];   // 128 rows x 8 chunks x 8 bf16, swizzled, 16KB
    __shared__ u16 Bs[8192];
    const int t = threadIdx.x;
    const int wave = t >> 6, lane = t & 63;
    const int wm = (wave >> 1) * 64, wn = (wave & 1) * 64;
    const int lhi = lane >> 4, llo = lane & 15;
    const int m0 = blockIdx.y * 128, n0 = blockIdx.x * 128;
    const int wbase = wave * 64;

    f32x4 acc[4][4] = {};

    for (int k0 = 0; k0 < K; k0 += 64) {
        const u16* Ab = A + (size_t)m0 * K + k0;
        const u16* Bb = Bt + (size_t)n0 * K + k0;
#pragma unroll
        for (int i = 0; i < 4; ++i) {
            int s = i * 256 + t;
            int row = s >> 3, gch = (s & 7) ^ (row & 7);
            dma16(Ab + (size_t)row * K + gch * 8, As + (i * 256 + wbase) * 8);
            dma16(Bb + (size_t)row * K + gch * 8, Bs + (i * 256 + wbase) * 8);
        }
        __syncthreads();
#pragma unroll
        for (int ks = 0; ks < 2; ++ks) {
            const int kb = ks * 4 + lhi;
            bf16x8 af[4], bfg[4];
#pragma unroll
            for (int mi = 0; mi < 4; ++mi) af[mi] = sfrag(As, wm + mi * 16 + llo, kb);
#pragma unroll
            for (int ni = 0; ni < 4; ++ni) bfg[ni] = sfrag(Bs, wn + ni * 16 + llo, kb);
#pragma unroll
            for (int mi = 0; mi < 4; ++mi)
#pragma unroll
                for (int ni = 0; ni < 4; ++ni)
                    acc[mi][ni] = __builtin_amdgcn_mfma_f32_16x16x32_bf16(
                        af[mi], bfg[ni], acc[mi][ni], 0, 0, 0);
        }
        __syncthreads();
    }

#pragma unroll
    for (int mi = 0; mi < 4; ++mi)
#pragma unroll
        for (int ni = 0; ni < 4; ++ni)
#pragma unroll
            for (int r = 0; r < 4; ++r) {
                int row = m0 + wm + mi * 16 + lhi * 4 + r;
                int col = n0 + wn + ni * 16 + llo;
                if (epi) ((float*)C)[(size_t)row * N + col] = acc[mi][ni][r];
                else     ((u16*)C)[(size_t)row * N + col] = f2bf(acc[mi][ni][r]);
            }
}

// ---------------- merged K/V projection ----------------
// bx<4: K = x@Wk^T  plain [4096][512] bf16
// bx>=4: V = x@Wv^T written TRANSPOSED: Vt[b][g][hd][s] (b=row>>11, s=row&2047)
__global__ __launch_bounds__(256) void gemm_kv(const u16* __restrict__ A,
                                               const u16* __restrict__ Wk,
                                               const u16* __restrict__ Wv,
                                               u16* __restrict__ Kout,
                                               u16* __restrict__ Vtout, int K) {
    __shared__ u16 As[8192];
    __shared__ u16 Bs[8192];
    const int t = threadIdx.x;
    const int wave = t >> 6, lane = t & 63;
    const int wm = (wave >> 1) * 64, wn = (wave & 1) * 64;
    const int lhi = lane >> 4, llo = lane & 15;
    const int m0 = blockIdx.y * 128;
    const bool vside = blockIdx.x >= 4;
    const int n0 = (blockIdx.x & 3) * 128;
    const u16* Bt = (vside ? Wv : Wk) + (size_t)n0 * K;
    const int wbase = wave * 64;

    f32x4 acc[4][4] = {};

    for (int k0 = 0; k0 < K; k0 += 64) {
        const u16* Ab = A + (size_t)m0 * K + k0;
        const u16* Bb = Bt + k0;
#pragma unroll
        for (int i = 0; i < 4; ++i) {
            int s = i * 256 + t;
            int row = s >> 3, gch = (s & 7) ^ (row & 7);
            dma16(Ab + (size_t)row * K + gch * 8, As + (i * 256 + wbase) * 8);
            dma16(Bb + (size_t)row * K + gch * 8, Bs + (i * 256 + wbase) * 8);
        }
        __syncthreads();
#pragma unroll
        for (int ks = 0; ks < 2; ++ks) {
            const int kb = ks * 4 + lhi;
            bf16x8 af[4], bfg[4];
#pragma unroll
            for (int mi = 0; mi < 4; ++mi) af[mi] = sfrag(As, wm + mi * 16 + llo, kb);
#pragma unroll
            for (int ni = 0; ni < 4; ++ni) bfg[ni] = sfrag(Bs, wn + ni * 16 + llo, kb);
#pragma unroll
            for (int mi = 0; mi < 4; ++mi)
#pragma unroll
                for (int ni = 0; ni < 4; ++ni)
                    acc[mi][ni] = __builtin_amdgcn_mfma_f32_16x16x32_bf16(
                        af[mi], bfg[ni], acc[mi][ni], 0, 0, 0);
        }
        __syncthreads();
    }

    if (!vside) {
#pragma unroll
        for (int mi = 0; mi < 4; ++mi)
#pragma unroll
            for (int ni = 0; ni < 4; ++ni)
#pragma unroll
                for (int r = 0; r < 4; ++r) {
                    int row = m0 + wm + mi * 16 + lhi * 4 + r;
                    int col = n0 + wn + ni * 16 + llo;
                    Kout[(size_t)row * 512 + col] = f2bf(acc[mi][ni][r]);
                }
    } else {
        // Vt[b][g][hd][s]: offset = (col + (row>>11)*512)*2048 + (row&2047)
#pragma unroll
        for (int mi = 0; mi < 4; ++mi)
#pragma unroll
            for (int ni = 0; ni < 4; ++ni) {
                int row = m0 + wm + mi * 16 + lhi * 4;   // 4-aligned
                int col = n0 + wn + ni * 16 + llo;       // 0..511
                size_t off = ((size_t)col + (size_t)(row >> 11) * 512) * 2048 + (row & 2047);
                short4 v;
                v.x = (short)f2bf(acc[mi][ni][0]);
                v.y = (short)f2bf(acc[mi][ni][1]);
                v.z = (short)f2bf(acc[mi][ni][2]);
                v.w = (short)f2bf(acc[mi][ni][3]);
                *(short4*)(Vtout + off) = v;
            }
    }
}

// ---------------- flash GQA attention v2 ----------------
// grid: x = q-tile of 32 rows (64), y = b*8+g (16). 4 waves = 4 heads of the group.
// Q: bf16 [b*2048+s][2048]; K: bf16 [b*2048+s][512]; Vt: bf16 [(b*8+g)*64+hd][2048]
__global__ __launch_bounds__(256) void attn2(const u16* __restrict__ Q,
                                             const u16* __restrict__ Kb,
                                             const u16* __restrict__ Vt,
                                             u16* __restrict__ Ctx) {
    __shared__ u16 Ks[4096];        // 64 seq-rows x 8 hd-chunks, swizzled, 8KB
    __shared__ u16 Vs[4096];        // 64 hd-rows x 8 seq-chunks, swizzled, 8KB
    __shared__ u16 Ps[4][32][72];   // per-wave P (32 q x 64 k), padded, 18KB
    const int qt = blockIdx.x;      // 0..63
    const int bg = blockIdx.y;      // 0..15
    const int b = bg >> 3, g = bg & 7;
    const int t = threadIdx.x, w = t >> 6, lane = t & 63;
    const int lhi = lane >> 4, llo = lane & 15;
    const int h = g * 4 + w;
    const int wbase = w * 64;

    // Q fragments in registers (read once)
    const u16* Qp = Q + ((size_t)(b * 2048 + qt * 32)) * 2048 + h * 64;
    bf16x8 aq[2][2];
#pragma unroll
    for (int mi = 0; mi < 2; ++mi)
#pragma unroll
        for (int ks = 0; ks < 2; ++ks)
            aq[mi][ks] = *(const bf16x8*)(Qp + (size_t)(mi * 16 + llo) * 2048 + ks * 32 + lhi * 8);

    const u16* Kp = Kb + (size_t)(b * 2048) * 512 + g * 64;
    const u16* Vp = Vt + (size_t)bg * 64 * 2048;

    f32x4 o[2][4] = {};
    float m_[2][4], l_[2][4];
#pragma unroll
    for (int mi = 0; mi < 2; ++mi)
#pragma unroll
        for (int r = 0; r < 4; ++r) { m_[mi][r] = NEG_BIG; l_[mi][r] = 0.f; }

    const int ktmax = (qt * 32 + 31) >> 6;
    for (int kt = 0; kt <= ktmax; ++kt) {
        __syncthreads();   // Ks/Vs safe to overwrite
#pragma unroll
        for (int i = 0; i < 2; ++i) {
            int s = i * 256 + t;
            int row = s >> 3, gch = (s & 7) ^ (row & 7);
            dma16(Kp + (size_t)(kt * 64 + row) * 512 + gch * 8, Ks + (i * 256 + wbase) * 8);
            dma16(Vp + (size_t)row * 2048 + (size_t)kt * 64 + gch * 8, Vs + (i * 256 + wbase) * 8);
        }
        __syncthreads();

        // S = Q K^T : per-wave 32q x 64k
        f32x4 st[2][4] = {};
#pragma unroll
        for (int ks = 0; ks < 2; ++ks) {
            const int kb = ks * 4 + lhi;
            bf16x8 bk[4];
#pragma unroll
            for (int nb = 0; nb < 4; ++nb) bk[nb] = sfrag(Ks, nb * 16 + llo, kb);
#pragma unroll
            for (int mi = 0; mi < 2; ++mi)
#pragma unroll
                for (int nb = 0; nb < 4; ++nb)
                    st[mi][nb] = __builtin_amdgcn_mfma_f32_16x16x32_bf16(
                        aq[mi][ks], bk[nb], st[mi][nb], 0, 0, 0);
        }

        // online softmax (all-finite)
        const bool needmask = (kt * 64 + 63) > (qt * 32);
        float sv[2][4][4], rmax[2][4];
#pragma unroll
        for (int mi = 0; mi < 2; ++mi)
#pragma unroll
            for (int r = 0; r < 4; ++r) rmax[mi][r] = NEG_BIG;
#pragma unroll
        for (int mi = 0; mi < 2; ++mi)
#pragma unroll
            for (int nb = 0; nb < 4; ++nb)
#pragma unroll
                for (int r = 0; r < 4; ++r) {
                    float v = st[mi][nb][r] * 0.125f;   // 1/sqrt(64)
                    if (needmask) {
                        int qrow = qt * 32 + mi * 16 + lhi * 4 + r;
                        int kcol = kt * 64 + nb * 16 + llo;
                        if (kcol > qrow) v = NEG_BIG;
                    }
                    sv[mi][nb][r] = v;
                    rmax[mi][r] = fmaxf(rmax[mi][r], v);
                }
#pragma unroll
        for (int msk = 1; msk < 16; msk <<= 1)
#pragma unroll
            for (int mi = 0; mi < 2; ++mi)
#pragma unroll
                for (int r = 0; r < 4; ++r)
                    rmax[mi][r] = fmaxf(rmax[mi][r], __shfl_xor(rmax[mi][r], msk, 64));

        float alpha[2][4], rsum[2][4];
#pragma unroll
        for (int mi = 0; mi < 2; ++mi)
#pragma unroll
            for (int r = 0; r < 4; ++r) {
                float mn = fmaxf(m_[mi][r], rmax[mi][r]);
                alpha[mi][r] = exp2f((m_[mi][r] - mn) * LOG2E);
                m_[mi][r] = mn;
                rsum[mi][r] = 0.f;
            }
#pragma unroll
        for (int mi = 0; mi < 2; ++mi)
#pragma unroll
            for (int nb = 0; nb < 4; ++nb)
#pragma unroll
                for (int r = 0; r < 4; ++r) {
                    float p = exp2f((sv[mi][nb][r] - m_[mi][r]) * LOG2E);
                    rsum[mi][r] += p;
                    Ps[w][mi * 16 + lhi * 4 + r][nb * 16 + llo] = f2bf(p);
                }
#pragma unroll
        for (int msk = 1; msk < 16; msk <<= 1)
#pragma unroll
            for (int mi = 0; mi < 2; ++mi)
#pragma unroll
                for (int r = 0; r < 4; ++r)
                    rsum[mi][r] += __shfl_xor(rsum[mi][r], msk, 64);
#pragma unroll
        for (int mi = 0; mi < 2; ++mi)
#pragma unroll
            for (int r = 0; r < 4; ++r)
                l_[mi][r] = l_[mi][r] * alpha[mi][r] + rsum[mi][r];
#pragma unroll
        for (int mi = 0; mi < 2; ++mi)
#pragma unroll
            for (int hb = 0; hb < 4; ++hb)
#pragma unroll
                for (int r = 0; r < 4; ++r) o[mi][hb][r] *= alpha[mi][r];

        __syncthreads();   // P visible before fragment reads

        // O += P @ V
#pragma unroll
        for (int ks2 = 0; ks2 < 2; ++ks2) {
            const int kb = ks2 * 4 + lhi;
            bf16x8 ap[2], bv[4];
#pragma unroll
            for (int mi = 0; mi < 2; ++mi)
                ap[mi] = *(const bf16x8*)(&Ps[w][mi * 16 + llo][ks2 * 32 + lhi * 8]);
#pragma unroll
            for (int hb = 0; hb < 4; ++hb) bv[hb] = sfrag(Vs, hb * 16 + llo, kb);
#pragma unroll
            for (int mi = 0; mi < 2; ++mi)
#pragma unroll
                for (int hb = 0; hb < 4; ++hb)
                    o[mi][hb] = __builtin_amdgcn_mfma_f32_16x16x32_bf16(
                        ap[mi], bv[hb], o[mi][hb], 0, 0, 0);
        }
    }

    u16* Cp = Ctx + (size_t)(b * 2048 + qt * 32) * 2048 + h * 64;
#pragma unroll
    for (int mi = 0; mi < 2; ++mi)
#pragma unroll
        for (int hb = 0; hb < 4; ++hb)
#pragma unroll
            for (int r = 0; r < 4; ++r) {
                int row = mi * 16 + lhi * 4 + r;
                int col = hb * 16 + llo;
                Cp[(size_t)row * 2048 + col] = f2bf(o[mi][hb][r] / l_[mi][r]);
            }
}

extern "C" void kernel_launch(void* const* d_in, const int* in_sizes, int n_in,
                              void* d_out, int out_size, void* d_ws, size_t ws_size,
                              hipStream_t stream) {
    const float* x  = (const float*)d_in[0];   // [2,2048,2048] fp32
    const float* Wq = (const float*)d_in[1];   // [2048,2048]
    const float* Wk = (const float*)d_in[2];   // [512,2048]
    const float* Wv = (const float*)d_in[3];   // [512,2048]
    const float* Wo = (const float*)d_in[4];   // [2048,2048]

    // ws layout (u16 elems), total 46.1 MB:
    // xb 8388608 | wqb 4194304 | wkb 1048576 | wvb 1048576 | wob 4194304 | K 2097152 | Vt 2097152
    // Ctx (8388608) overlays xb (dead after the projections).
    u16* xb  = (u16*)d_ws;
    u16* wqb = xb + 8388608;
    u16* wkb = wqb + 4194304;
    u16* wvb = wkb + 1048576;
    u16* wob = wvb + 1048576;
    u16* Kb  = wob + 4194304;
    u16* Vtb = Kb + 2097152;
    u16* Ctx = xb;               // overlay
    u16* Qb  = (u16*)d_out;      // 16MB bf16 in 32MB fp32 out buffer; dead before final GEMM
    float* out = (float*)d_out;

    cvt<<<dim3(8388608 / 8 / 256), 256, 0, stream>>>(x, xb, 8388608 / 8);
    cvt<<<dim3(4194304 / 8 / 256), 256, 0, stream>>>(Wq, wqb, 4194304 / 8);
    cvt<<<dim3(1048576 / 8 / 256), 256, 0, stream>>>(Wk, wkb, 1048576 / 8);
    cvt<<<dim3(1048576 / 8 / 256), 256, 0, stream>>>(Wv, wvb, 1048576 / 8);
    cvt<<<dim3(4194304 / 8 / 256), 256, 0, stream>>>(Wo, wob, 4194304 / 8);

    gemm_bt<<<dim3(16, 32), 256, 0, stream>>>(xb, wqb, Qb, 4096, 2048, 2048, 0);
    gemm_kv<<<dim3(8, 32), 256, 0, stream>>>(xb, wkb, wvb, Kb, Vtb, 2048);
    attn2<<<dim3(64, 16), 256, 0, stream>>>(Qb, Kb, Vtb, Ctx);
    gemm_bt<<<dim3(16, 32), 256, 0, stream>>>(Ctx, wob, out, 4096, 2048, 2048, 1);
}

// Round 5
// 387.689 us; speedup vs baseline: 2.4376x; 1.5140x over previous
//
#include <hip/hip_runtime.h>
#include <hip/hip_bf16.h>

typedef unsigned short u16;
typedef short bf16x8 __attribute__((ext_vector_type(8)));
typedef float f32x4 __attribute__((ext_vector_type(4)));

#define NEG_BIG (-1e30f)
#define SCL 0.18033688f   // 0.125 * log2(e): scores scaled to log2 units

__device__ __forceinline__ u16 f2bf(float f) {
    union { float f; unsigned int u; } x; x.f = f;
    unsigned int r = x.u + 0x7fffu + ((x.u >> 16) & 1u);
    return (u16)(r >> 16);
}

__device__ __forceinline__ void dma16(const u16* g, const u16* lds) {
    __builtin_amdgcn_global_load_lds(
        (const __attribute__((address_space(1))) unsigned int*)g,
        (__attribute__((address_space(3))) unsigned int*)lds, 16, 0, 0);
}

__device__ __forceinline__ bf16x8 sfrag(const u16* lds, int row, int kb8) {
    int slot = row * 8 + (kb8 ^ (row & 7));
    return *(const bf16x8*)(lds + slot * 8);
}

// ---------------- fused fp32 -> bf16 convert (all 5 tensors, 1 launch) ----------------
__global__ __launch_bounds__(256) void cvt_all(const float* __restrict__ x,
                                               const float* __restrict__ wq,
                                               const float* __restrict__ wk,
                                               const float* __restrict__ wv,
                                               const float* __restrict__ wo,
                                               u16* __restrict__ xb, u16* __restrict__ wqb,
                                               u16* __restrict__ wkb, u16* __restrict__ wvb,
                                               u16* __restrict__ wob) {
    size_t i = (size_t)blockIdx.x * 256 + threadIdx.x;   // 8-elem chunk id
    const float* s; u16* d; size_t off;
    if      (i < 1048576) { s = x;  d = xb;  off = i; }
    else if (i < 1572864) { s = wq; d = wqb; off = i - 1048576; }
    else if (i < 1703936) { s = wk; d = wkb; off = i - 1572864; }
    else if (i < 1835008) { s = wv; d = wvb; off = i - 1703936; }
    else                  { s = wo; d = wob; off = i - 1835008; }
    const float* p = s + off * 8;
    float4 a = *(const float4*)p;
    float4 b = *(const float4*)(p + 4);
    bf16x8 r;
    r[0] = (short)f2bf(a.x); r[1] = (short)f2bf(a.y);
    r[2] = (short)f2bf(a.z); r[3] = (short)f2bf(a.w);
    r[4] = (short)f2bf(b.x); r[5] = (short)f2bf(b.y);
    r[6] = (short)f2bf(b.z); r[7] = (short)f2bf(b.w);
    *(bf16x8*)(d + off * 8) = r;
}

// ---------------- bf16 GEMM (m97-style), fp32 output ----------------
__global__ __launch_bounds__(256) void gemm_bt(const u16* __restrict__ A,
                                               const u16* __restrict__ Bt,
                                               float* __restrict__ C,
                                               int M, int N, int K) {
    __shared__ u16 As[8192];
    __shared__ u16 Bs[8192];
    const int t = threadIdx.x;
    const int wave = t >> 6, lane = t & 63;
    const int wm = (wave >> 1) * 64, wn = (wave & 1) * 64;
    const int lhi = lane >> 4, llo = lane & 15;
    const int m0 = blockIdx.y * 128, n0 = blockIdx.x * 128;
    const int wbase = wave * 64;

    f32x4 acc[4][4] = {};
    for (int k0 = 0; k0 < K; k0 += 64) {
        const u16* Ab = A + (size_t)m0 * K + k0;
        const u16* Bb = Bt + (size_t)n0 * K + k0;
#pragma unroll
        for (int i = 0; i < 4; ++i) {
            int s = i * 256 + t;
            int row = s >> 3, gch = (s & 7) ^ (row & 7);
            dma16(Ab + (size_t)row * K + gch * 8, As + (i * 256 + wbase) * 8);
            dma16(Bb + (size_t)row * K + gch * 8, Bs + (i * 256 + wbase) * 8);
        }
        __syncthreads();
#pragma unroll
        for (int ks = 0; ks < 2; ++ks) {
            const int kb = ks * 4 + lhi;
            bf16x8 af[4], bfg[4];
#pragma unroll
            for (int mi = 0; mi < 4; ++mi) af[mi] = sfrag(As, wm + mi * 16 + llo, kb);
#pragma unroll
            for (int ni = 0; ni < 4; ++ni) bfg[ni] = sfrag(Bs, wn + ni * 16 + llo, kb);
#pragma unroll
            for (int mi = 0; mi < 4; ++mi)
#pragma unroll
                for (int ni = 0; ni < 4; ++ni)
                    acc[mi][ni] = __builtin_amdgcn_mfma_f32_16x16x32_bf16(
                        af[mi], bfg[ni], acc[mi][ni], 0, 0, 0);
        }
        __syncthreads();
    }
#pragma unroll
    for (int mi = 0; mi < 4; ++mi)
#pragma unroll
        for (int ni = 0; ni < 4; ++ni)
#pragma unroll
            for (int r = 0; r < 4; ++r) {
                int row = m0 + wm + mi * 16 + lhi * 4 + r;
                int col = n0 + wn + ni * 16 + llo;
                C[(size_t)row * N + col] = acc[mi][ni][r];
            }
}

// ---------------- merged Q/K/V projection ----------------
// bx 0..15: Q [4096][2048] bf16 | bx 16..19: K [4096][512] bf16 |
// bx 20..23: Vt[b][g][hd][s] bf16 (transposed epilogue)
__global__ __launch_bounds__(256) void gemm_qkv(const u16* __restrict__ A,
                                                const u16* __restrict__ Wq,
                                                const u16* __restrict__ Wk,
                                                const u16* __restrict__ Wv,
                                                u16* __restrict__ Qout,
                                                u16* __restrict__ Kout,
                                                u16* __restrict__ Vtout) {
    const int K = 2048;
    __shared__ u16 As[8192];
    __shared__ u16 Bs[8192];
    const int t = threadIdx.x;
    const int wave = t >> 6, lane = t & 63;
    const int wm = (wave >> 1) * 64, wn = (wave & 1) * 64;
    const int lhi = lane >> 4, llo = lane & 15;
    const int m0 = blockIdx.y * 128;
    const int bx = blockIdx.x;
    const int kind = (bx < 16) ? 0 : (bx < 20 ? 1 : 2);
    const int n0 = (kind == 0) ? bx * 128 : (bx & 3) * 128;
    const u16* Bt = ((kind == 0) ? Wq : (kind == 1) ? Wk : Wv) + (size_t)n0 * K;
    const int wbase = wave * 64;

    f32x4 acc[4][4] = {};
    for (int k0 = 0; k0 < K; k0 += 64) {
        const u16* Ab = A + (size_t)m0 * K + k0;
        const u16* Bb = Bt + k0;
#pragma unroll
        for (int i = 0; i < 4; ++i) {
            int s = i * 256 + t;
            int row = s >> 3, gch = (s & 7) ^ (row & 7);
            dma16(Ab + (size_t)row * K + gch * 8, As + (i * 256 + wbase) * 8);
            dma16(Bb + (size_t)row * K + gch * 8, Bs + (i * 256 + wbase) * 8);
        }
        __syncthreads();
#pragma unroll
        for (int ks = 0; ks < 2; ++ks) {
            const int kb = ks * 4 + lhi;
            bf16x8 af[4], bfg[4];
#pragma unroll
            for (int mi = 0; mi < 4; ++mi) af[mi] = sfrag(As, wm + mi * 16 + llo, kb);
#pragma unroll
            for (int ni = 0; ni < 4; ++ni) bfg[ni] = sfrag(Bs, wn + ni * 16 + llo, kb);
#pragma unroll
            for (int mi = 0; mi < 4; ++mi)
#pragma unroll
                for (int ni = 0; ni < 4; ++ni)
                    acc[mi][ni] = __builtin_amdgcn_mfma_f32_16x16x32_bf16(
                        af[mi], bfg[ni], acc[mi][ni], 0, 0, 0);
        }
        __syncthreads();
    }

    if (kind == 0) {
#pragma unroll
        for (int mi = 0; mi < 4; ++mi)
#pragma unroll
            for (int ni = 0; ni < 4; ++ni)
#pragma unroll
                for (int r = 0; r < 4; ++r) {
                    int row = m0 + wm + mi * 16 + lhi * 4 + r;
                    int col = n0 + wn + ni * 16 + llo;
                    Qout[(size_t)row * 2048 + col] = f2bf(acc[mi][ni][r]);
                }
    } else if (kind == 1) {
#pragma unroll
        for (int mi = 0; mi < 4; ++mi)
#pragma unroll
            for (int ni = 0; ni < 4; ++ni)
#pragma unroll
                for (int r = 0; r < 4; ++r) {
                    int row = m0 + wm + mi * 16 + lhi * 4 + r;
                    int col = n0 + wn + ni * 16 + llo;
                    Kout[(size_t)row * 512 + col] = f2bf(acc[mi][ni][r]);
                }
    } else {
        // Vt[b][g][hd][s]: off = (col + (row>>11)*512)*2048 + (row&2047)
#pragma unroll
        for (int mi = 0; mi < 4; ++mi)
#pragma unroll
            for (int ni = 0; ni < 4; ++ni) {
                int row = m0 + wm + mi * 16 + lhi * 4;
                int col = n0 + wn + ni * 16 + llo;
                size_t off = ((size_t)col + (size_t)(row >> 11) * 512) * 2048 + (row & 2047);
                short4 v;
                v.x = (short)f2bf(acc[mi][ni][0]);
                v.y = (short)f2bf(acc[mi][ni][1]);
                v.z = (short)f2bf(acc[mi][ni][2]);
                v.w = (short)f2bf(acc[mi][ni][3]);
                *(short4*)(Vtout + off) = v;
            }
    }
}

// ---------------- flash GQA attention v3: S^T layout ----------------
// grid: x -> qt = 63 - x (longest first), y = b*8+g. 4 waves = 4 heads of group.
// S^T = K·Q^T (A=K-frag, B=Q-frag): lane holds q = llo (scalar!), k = lhi*4+r.
// O^T = Vt·P (A=Vs[hd][s], B=P[q][s]) -> lane holds q=llo, hd=lhi*4+r.
__global__ __launch_bounds__(256, 4) void attn3(const u16* __restrict__ Q,
                                                const u16* __restrict__ Kb,
                                                const u16* __restrict__ Vt,
                                                u16* __restrict__ Ctx) {
    __shared__ u16 Ks[4096];        // 64 k-rows x 8 hd-chunks, swizzled
    __shared__ u16 Vs[4096];        // 64 hd-rows x 8 s-chunks, swizzled
    __shared__ u16 Pl[4][32][72];   // per-wave P[q][s], padded
    const int qt = 63 - blockIdx.x;
    const int bg = blockIdx.y;
    const int b = bg >> 3, g = bg & 7;
    const int t = threadIdx.x, w = t >> 6, lane = t & 63;
    const int lhi = lane >> 4, llo = lane & 15;
    const int h = g * 4 + w;
    const int wbase = w * 64;

    // Q B-operand fragments in registers: B[n=q][k=hd]
    const u16* Qp = Q + ((size_t)(b * 2048 + qt * 32)) * 2048 + h * 64;
    bf16x8 aq[2][2];
#pragma unroll
    for (int qb = 0; qb < 2; ++qb)
#pragma unroll
        for (int ks = 0; ks < 2; ++ks)
            aq[qb][ks] = *(const bf16x8*)(Qp + (size_t)(qb * 16 + llo) * 2048 + ks * 32 + lhi * 8);

    const u16* Kp = Kb + (size_t)(b * 2048) * 512 + g * 64;
    const u16* Vp = Vt + (size_t)bg * 64 * 2048;

    f32x4 o[4][2] = {};          // O^T: [hd-tile][q-tile]
    float m_[2], l_[2];          // per-lane scalars (q = qb*16 + llo)
#pragma unroll
    for (int qb = 0; qb < 2; ++qb) { m_[qb] = NEG_BIG; l_[qb] = 0.f; }

    const int ktmax = (qt * 32 + 31) >> 6;
    for (int kt = 0; kt <= ktmax; ++kt) {
        __syncthreads();
#pragma unroll
        for (int i = 0; i < 2; ++i) {
            int s = i * 256 + t;
            int row = s >> 3, gch = (s & 7) ^ (row & 7);
            dma16(Kp + (size_t)(kt * 64 + row) * 512 + gch * 8, Ks + (i * 256 + wbase) * 8);
            dma16(Vp + (size_t)row * 2048 + (size_t)kt * 64 + gch * 8, Vs + (i * 256 + wbase) * 8);
        }
        __syncthreads();

        // S^T = K Q^T : st[kb][qb], D[m=k][n=q]
        f32x4 st[4][2] = {};
#pragma unroll
        for (int ks = 0; ks < 2; ++ks) {
            const int kb8 = ks * 4 + lhi;
            bf16x8 kf[4];
#pragma unroll
            for (int kb = 0; kb < 4; ++kb) kf[kb] = sfrag(Ks, kb * 16 + llo, kb8);
#pragma unroll
            for (int kb = 0; kb < 4; ++kb)
#pragma unroll
                for (int qb = 0; qb < 2; ++qb)
                    st[kb][qb] = __builtin_amdgcn_mfma_f32_16x16x32_bf16(
                        kf[kb], aq[qb][ks], st[kb][qb], 0, 0, 0);
        }

        // scale to log2 units + causal mask (in place)
        const bool needmask = (kt * 64 + 63) > (qt * 32);
#pragma unroll
        for (int kb = 0; kb < 4; ++kb)
#pragma unroll
            for (int qb = 0; qb < 2; ++qb)
#pragma unroll
                for (int r = 0; r < 4; ++r) {
                    float v = st[kb][qb][r] * SCL;
                    if (needmask) {
                        int kg = kt * 64 + kb * 16 + lhi * 4 + r;
                        int qg = qt * 32 + qb * 16 + llo;
                        if (kg > qg) v = NEG_BIG;
                    }
                    st[kb][qb][r] = v;
                }

        // per-q max: 15 in-lane + 2 shfl (reduction only across lhi)
        float rmax[2], alpha[2], rsum[2];
#pragma unroll
        for (int qb = 0; qb < 2; ++qb) {
            float mx = st[0][qb][0];
#pragma unroll
            for (int kb = 0; kb < 4; ++kb)
#pragma unroll
                for (int r = 0; r < 4; ++r) mx = fmaxf(mx, st[kb][qb][r]);
            mx = fmaxf(mx, __shfl_xor(mx, 16, 64));
            mx = fmaxf(mx, __shfl_xor(mx, 32, 64));
            rmax[qb] = mx;
            float mn = fmaxf(m_[qb], mx);
            alpha[qb] = exp2f(m_[qb] - mn);
            m_[qb] = mn;
            rsum[qb] = 0.f;
        }

        // p = exp2(s - m); store P[q][s] to wave-private LDS
#pragma unroll
        for (int kb = 0; kb < 4; ++kb)
#pragma unroll
            for (int qb = 0; qb < 2; ++qb) {
                short4 pk;
                float p0 = exp2f(st[kb][qb][0] - m_[qb]);
                float p1 = exp2f(st[kb][qb][1] - m_[qb]);
                float p2 = exp2f(st[kb][qb][2] - m_[qb]);
                float p3 = exp2f(st[kb][qb][3] - m_[qb]);
                rsum[qb] += (p0 + p1) + (p2 + p3);
                pk.x = (short)f2bf(p0); pk.y = (short)f2bf(p1);
                pk.z = (short)f2bf(p2); pk.w = (short)f2bf(p3);
                *(short4*)(&Pl[w][qb * 16 + llo][kb * 16 + lhi * 4]) = pk;
            }
#pragma unroll
        for (int qb = 0; qb < 2; ++qb) {
            rsum[qb] += __shfl_xor(rsum[qb], 16, 64);
            rsum[qb] += __shfl_xor(rsum[qb], 32, 64);
            l_[qb] = l_[qb] * alpha[qb] + rsum[qb];
        }
#pragma unroll
        for (int hb = 0; hb < 4; ++hb)
#pragma unroll
            for (int qb = 0; qb < 2; ++qb)
#pragma unroll
                for (int r = 0; r < 4; ++r) o[hb][qb][r] *= alpha[qb];

        // wave-private P: lgkmcnt(0) drain suffices (no barrier)
        __builtin_amdgcn_s_waitcnt(0xC07F);

        // O^T += Vt-tile · P : A=Vs[hd][s], B=Pl[q][s]
#pragma unroll
        for (int ks2 = 0; ks2 < 2; ++ks2) {
            bf16x8 pf[2], vf[4];
#pragma unroll
            for (int qb = 0; qb < 2; ++qb)
                pf[qb] = *(const bf16x8*)(&Pl[w][qb * 16 + llo][ks2 * 32 + lhi * 8]);
#pragma unroll
            for (int hb = 0; hb < 4; ++hb) vf[hb] = sfrag(Vs, hb * 16 + llo, ks2 * 4 + lhi);
#pragma unroll
            for (int hb = 0; hb < 4; ++hb)
#pragma unroll
                for (int qb = 0; qb < 2; ++qb)
                    o[hb][qb] = __builtin_amdgcn_mfma_f32_16x16x32_bf16(
                        vf[hb], pf[qb], o[hb][qb], 0, 0, 0);
        }
    }

    // epilogue: lane holds q = qt*32+qb*16+llo, hd = hb*16+lhi*4+r -> short4 store
    u16* Cp = Ctx + (size_t)(b * 2048 + qt * 32) * 2048 + h * 64;
#pragma unroll
    for (int qb = 0; qb < 2; ++qb) {
        float inv0 = 1.0f / l_[qb];
#pragma unroll
        for (int hb = 0; hb < 4; ++hb) {
            short4 v;
            v.x = (short)f2bf(o[hb][qb][0] * inv0);
            v.y = (short)f2bf(o[hb][qb][1] * inv0);
            v.z = (short)f2bf(o[hb][qb][2] * inv0);
            v.w = (short)f2bf(o[hb][qb][3] * inv0);
            *(short4*)(Cp + (size_t)(qb * 16 + llo) * 2048 + hb * 16 + lhi * 4) = v;
        }
    }
}

extern "C" void kernel_launch(void* const* d_in, const int* in_sizes, int n_in,
                              void* d_out, int out_size, void* d_ws, size_t ws_size,
                              hipStream_t stream) {
    const float* x  = (const float*)d_in[0];
    const float* Wq = (const float*)d_in[1];
    const float* Wk = (const float*)d_in[2];
    const float* Wv = (const float*)d_in[3];
    const float* Wo = (const float*)d_in[4];

    u16* xb  = (u16*)d_ws;
    u16* wqb = xb + 8388608;
    u16* wkb = wqb + 4194304;
    u16* wvb = wkb + 1048576;
    u16* wob = wvb + 1048576;
    u16* Kb  = wob + 4194304;
    u16* Vtb = Kb + 2097152;
    u16* Ctx = xb;               // overlay (xb dead after projections)
    u16* Qb  = (u16*)d_out;      // bf16 Q staged in fp32 out buffer
    float* out = (float*)d_out;

    cvt_all<<<dim3(9216), 256, 0, stream>>>(x, Wq, Wk, Wv, Wo, xb, wqb, wkb, wvb, wob);
    gemm_qkv<<<dim3(24, 32), 256, 0, stream>>>(xb, wqb, wkb, wvb, Qb, Kb, Vtb);
    attn3<<<dim3(64, 16), 256, 0, stream>>>(Qb, Kb, Vtb, Ctx);
    gemm_bt<<<dim3(16, 32), 256, 0, stream>>>(Ctx, wob, out, 4096, 2048, 2048);
}

// Round 6
// 342.205 us; speedup vs baseline: 2.7616x; 1.1329x over previous
//
#include <hip/hip_runtime.h>
#include <hip/hip_bf16.h>

typedef unsigned short u16;
typedef short bf16x8 __attribute__((ext_vector_type(8)));
typedef float f32x4 __attribute__((ext_vector_type(4)));

#define NEG_BIG (-1e30f)
#define SCL 0.18033688f   // 0.125 * log2(e): Q pre-scaled so scores are in log2 units

__device__ __forceinline__ u16 f2bf(float f) {
    union { float f; unsigned int u; } x; x.f = f;
    unsigned int r = x.u + 0x7fffu + ((x.u >> 16) & 1u);
    return (u16)(r >> 16);
}

__device__ __forceinline__ void dma16(const u16* g, const u16* lds) {
    __builtin_amdgcn_global_load_lds(
        (const __attribute__((address_space(1))) unsigned int*)g,
        (__attribute__((address_space(3))) unsigned int*)lds, 16, 0, 0);
}

__device__ __forceinline__ bf16x8 sfrag(const u16* lds, int row, int kb8) {
    int slot = row * 8 + (kb8 ^ (row & 7));
    return *(const bf16x8*)(lds + slot * 8);
}

// ---------------- fused fp32 -> bf16 convert ----------------
__global__ __launch_bounds__(256) void cvt_all(const float* __restrict__ x,
                                               const float* __restrict__ wq,
                                               const float* __restrict__ wk,
                                               const float* __restrict__ wv,
                                               const float* __restrict__ wo,
                                               u16* __restrict__ xb, u16* __restrict__ wqb,
                                               u16* __restrict__ wkb, u16* __restrict__ wvb,
                                               u16* __restrict__ wob) {
    size_t i = (size_t)blockIdx.x * 256 + threadIdx.x;
    const float* s; u16* d; size_t off;
    if      (i < 1048576) { s = x;  d = xb;  off = i; }
    else if (i < 1572864) { s = wq; d = wqb; off = i - 1048576; }
    else if (i < 1703936) { s = wk; d = wkb; off = i - 1572864; }
    else if (i < 1835008) { s = wv; d = wvb; off = i - 1703936; }
    else                  { s = wo; d = wob; off = i - 1835008; }
    const float* p = s + off * 8;
    float4 a = *(const float4*)p;
    float4 b = *(const float4*)(p + 4);
    bf16x8 r;
    r[0] = (short)f2bf(a.x); r[1] = (short)f2bf(a.y);
    r[2] = (short)f2bf(a.z); r[3] = (short)f2bf(a.w);
    r[4] = (short)f2bf(b.x); r[5] = (short)f2bf(b.y);
    r[6] = (short)f2bf(b.z); r[7] = (short)f2bf(b.w);
    *(bf16x8*)(d + off * 8) = r;
}

// ---------------- bf16 GEMM (m97-style), fp32 output ----------------
__global__ __launch_bounds__(256) void gemm_bt(const u16* __restrict__ A,
                                               const u16* __restrict__ Bt,
                                               float* __restrict__ C,
                                               int M, int N, int K) {
    __shared__ u16 As[8192];
    __shared__ u16 Bs[8192];
    const int t = threadIdx.x;
    const int wave = t >> 6, lane = t & 63;
    const int wm = (wave >> 1) * 64, wn = (wave & 1) * 64;
    const int lhi = lane >> 4, llo = lane & 15;
    const int m0 = blockIdx.y * 128, n0 = blockIdx.x * 128;
    const int wbase = wave * 64;

    f32x4 acc[4][4] = {};
    for (int k0 = 0; k0 < K; k0 += 64) {
        const u16* Ab = A + (size_t)m0 * K + k0;
        const u16* Bb = Bt + (size_t)n0 * K + k0;
#pragma unroll
        for (int i = 0; i < 4; ++i) {
            int s = i * 256 + t;
            int row = s >> 3, gch = (s & 7) ^ (row & 7);
            dma16(Ab + (size_t)row * K + gch * 8, As + (i * 256 + wbase) * 8);
            dma16(Bb + (size_t)row * K + gch * 8, Bs + (i * 256 + wbase) * 8);
        }
        __syncthreads();
#pragma unroll
        for (int ks = 0; ks < 2; ++ks) {
            const int kb = ks * 4 + lhi;
            bf16x8 af[4], bfg[4];
#pragma unroll
            for (int mi = 0; mi < 4; ++mi) af[mi] = sfrag(As, wm + mi * 16 + llo, kb);
#pragma unroll
            for (int ni = 0; ni < 4; ++ni) bfg[ni] = sfrag(Bs, wn + ni * 16 + llo, kb);
#pragma unroll
            for (int mi = 0; mi < 4; ++mi)
#pragma unroll
                for (int ni = 0; ni < 4; ++ni)
                    acc[mi][ni] = __builtin_amdgcn_mfma_f32_16x16x32_bf16(
                        af[mi], bfg[ni], acc[mi][ni], 0, 0, 0);
        }
        __syncthreads();
    }
#pragma unroll
    for (int mi = 0; mi < 4; ++mi)
#pragma unroll
        for (int ni = 0; ni < 4; ++ni)
#pragma unroll
            for (int r = 0; r < 4; ++r) {
                int row = m0 + wm + mi * 16 + lhi * 4 + r;
                int col = n0 + wn + ni * 16 + llo;
                C[(size_t)row * N + col] = acc[mi][ni][r];
            }
}

// ---------------- merged Q/K/V projection ----------------
// bx 0..15: Q [4096][2048] bf16, PRE-SCALED by SCL | bx 16..19: K | bx 20..23: Vt
__global__ __launch_bounds__(256) void gemm_qkv(const u16* __restrict__ A,
                                                const u16* __restrict__ Wq,
                                                const u16* __restrict__ Wk,
                                                const u16* __restrict__ Wv,
                                                u16* __restrict__ Qout,
                                                u16* __restrict__ Kout,
                                                u16* __restrict__ Vtout) {
    const int K = 2048;
    __shared__ u16 As[8192];
    __shared__ u16 Bs[8192];
    const int t = threadIdx.x;
    const int wave = t >> 6, lane = t & 63;
    const int wm = (wave >> 1) * 64, wn = (wave & 1) * 64;
    const int lhi = lane >> 4, llo = lane & 15;
    const int m0 = blockIdx.y * 128;
    const int bx = blockIdx.x;
    const int kind = (bx < 16) ? 0 : (bx < 20 ? 1 : 2);
    const int n0 = (kind == 0) ? bx * 128 : (bx & 3) * 128;
    const u16* Bt = ((kind == 0) ? Wq : (kind == 1) ? Wk : Wv) + (size_t)n0 * K;
    const int wbase = wave * 64;

    f32x4 acc[4][4] = {};
    for (int k0 = 0; k0 < K; k0 += 64) {
        const u16* Ab = A + (size_t)m0 * K + k0;
        const u16* Bb = Bt + k0;
#pragma unroll
        for (int i = 0; i < 4; ++i) {
            int s = i * 256 + t;
            int row = s >> 3, gch = (s & 7) ^ (row & 7);
            dma16(Ab + (size_t)row * K + gch * 8, As + (i * 256 + wbase) * 8);
            dma16(Bb + (size_t)row * K + gch * 8, Bs + (i * 256 + wbase) * 8);
        }
        __syncthreads();
#pragma unroll
        for (int ks = 0; ks < 2; ++ks) {
            const int kb = ks * 4 + lhi;
            bf16x8 af[4], bfg[4];
#pragma unroll
            for (int mi = 0; mi < 4; ++mi) af[mi] = sfrag(As, wm + mi * 16 + llo, kb);
#pragma unroll
            for (int ni = 0; ni < 4; ++ni) bfg[ni] = sfrag(Bs, wn + ni * 16 + llo, kb);
#pragma unroll
            for (int mi = 0; mi < 4; ++mi)
#pragma unroll
                for (int ni = 0; ni < 4; ++ni)
                    acc[mi][ni] = __builtin_amdgcn_mfma_f32_16x16x32_bf16(
                        af[mi], bfg[ni], acc[mi][ni], 0, 0, 0);
        }
        __syncthreads();
    }

    if (kind == 0) {
#pragma unroll
        for (int mi = 0; mi < 4; ++mi)
#pragma unroll
            for (int ni = 0; ni < 4; ++ni)
#pragma unroll
                for (int r = 0; r < 4; ++r) {
                    int row = m0 + wm + mi * 16 + lhi * 4 + r;
                    int col = n0 + wn + ni * 16 + llo;
                    Qout[(size_t)row * 2048 + col] = f2bf(acc[mi][ni][r] * SCL);
                }
    } else if (kind == 1) {
#pragma unroll
        for (int mi = 0; mi < 4; ++mi)
#pragma unroll
            for (int ni = 0; ni < 4; ++ni)
#pragma unroll
                for (int r = 0; r < 4; ++r) {
                    int row = m0 + wm + mi * 16 + lhi * 4 + r;
                    int col = n0 + wn + ni * 16 + llo;
                    Kout[(size_t)row * 512 + col] = f2bf(acc[mi][ni][r]);
                }
    } else {
        // Vt[b][g][hd][s]: off = (col + (row>>11)*512)*2048 + (row&2047)
#pragma unroll
        for (int mi = 0; mi < 4; ++mi)
#pragma unroll
            for (int ni = 0; ni < 4; ++ni) {
                int row = m0 + wm + mi * 16 + lhi * 4;
                int col = n0 + wn + ni * 16 + llo;
                size_t off = ((size_t)col + (size_t)(row >> 11) * 512) * 2048 + (row & 2047);
                short4 v;
                v.x = (short)f2bf(acc[mi][ni][0]);
                v.y = (short)f2bf(acc[mi][ni][1]);
                v.z = (short)f2bf(acc[mi][ni][2]);
                v.w = (short)f2bf(acc[mi][ni][3]);
                *(short4*)(Vtout + off) = v;
            }
    }
}

// ---------------- flash GQA attention v4: S^T layout, 16-row q-tiles ----------------
// grid: x -> qt = 127 - x (longest first), y = b*8+g (16). 2048 blocks, 4 waves = 4 heads.
// Lane holds q = llo (scalar m/l), k(or hd) = lhi*4+r.
__global__ __launch_bounds__(256, 4) void attn4(const u16* __restrict__ Q,
                                                const u16* __restrict__ Kb,
                                                const u16* __restrict__ Vt,
                                                u16* __restrict__ Ctx) {
    __shared__ u16 Ks[4096];        // 64 k-rows x 8 hd-chunks, swizzled (8KB)
    __shared__ u16 Vs[4096];        // 64 hd-rows x 8 s-chunks, swizzled (8KB)
    __shared__ u16 Pl[4][16][72];   // per-wave P[q][s] (9KB)
    const int qt = 127 - blockIdx.x;    // 16-row q tile
    const int bg = blockIdx.y;
    const int b = bg >> 3, g = bg & 7;
    const int t = threadIdx.x, w = t >> 6, lane = t & 63;
    const int lhi = lane >> 4, llo = lane & 15;
    const int h = g * 4 + w;
    const int wbase = w * 64;

    // Q B-operand fragments (pre-scaled by SCL at projection time)
    const u16* Qp = Q + ((size_t)(b * 2048 + qt * 16)) * 2048 + h * 64;
    bf16x8 aq[2];
#pragma unroll
    for (int ks = 0; ks < 2; ++ks)
        aq[ks] = *(const bf16x8*)(Qp + (size_t)llo * 2048 + ks * 32 + lhi * 8);

    const u16* Kp = Kb + (size_t)(b * 2048) * 512 + g * 64;
    const u16* Vp = Vt + (size_t)bg * 64 * 2048;

    f32x4 o[4] = {};          // O^T: [hd-tile], lane q=llo, hd=hb*16+lhi*4+r
    float m_ = NEG_BIG, l_ = 0.f;

    const int ktmax = (qt * 16 + 15) >> 6;
    for (int kt = 0; kt <= ktmax; ++kt) {
        __syncthreads();
#pragma unroll
        for (int i = 0; i < 2; ++i) {
            int s = i * 256 + t;
            int row = s >> 3, gch = (s & 7) ^ (row & 7);
            dma16(Kp + (size_t)(kt * 64 + row) * 512 + gch * 8, Ks + (i * 256 + wbase) * 8);
            dma16(Vp + (size_t)row * 2048 + (size_t)kt * 64 + gch * 8, Vs + (i * 256 + wbase) * 8);
        }
        __syncthreads();

        // S^T = K Q^T : st[kb], D[m=k][n=q] (already in log2 units)
        f32x4 st[4] = {};
#pragma unroll
        for (int ks = 0; ks < 2; ++ks) {
            const int kb8 = ks * 4 + lhi;
            bf16x8 kf[4];
#pragma unroll
            for (int kb = 0; kb < 4; ++kb) kf[kb] = sfrag(Ks, kb * 16 + llo, kb8);
#pragma unroll
            for (int kb = 0; kb < 4; ++kb)
                st[kb] = __builtin_amdgcn_mfma_f32_16x16x32_bf16(
                    kf[kb], aq[ks], st[kb], 0, 0, 0);
        }

        // causal mask (uniform branch: only the diagonal tile pays)
        if (kt * 64 + 63 > qt * 16) {
            int qg = qt * 16 + llo;
#pragma unroll
            for (int kb = 0; kb < 4; ++kb)
#pragma unroll
                for (int r = 0; r < 4; ++r) {
                    int kg = kt * 64 + kb * 16 + lhi * 4 + r;
                    if (kg > qg) st[kb][r] = NEG_BIG;
                }
        }

        // per-q max: 16 in-lane fmax + 2 shfl
        float mx = st[0][0];
#pragma unroll
        for (int kb = 0; kb < 4; ++kb)
#pragma unroll
            for (int r = 0; r < 4; ++r) mx = fmaxf(mx, st[kb][r]);
        mx = fmaxf(mx, __shfl_xor(mx, 16, 64));
        mx = fmaxf(mx, __shfl_xor(mx, 32, 64));
        float mn = fmaxf(m_, mx);
        float alpha = exp2f(m_ - mn);
        m_ = mn;
        float rsum = 0.f;

        // p = exp2(s - m); store P[q][s] to wave-private LDS
#pragma unroll
        for (int kb = 0; kb < 4; ++kb) {
            float p0 = exp2f(st[kb][0] - m_);
            float p1 = exp2f(st[kb][1] - m_);
            float p2 = exp2f(st[kb][2] - m_);
            float p3 = exp2f(st[kb][3] - m_);
            rsum += (p0 + p1) + (p2 + p3);
            short4 pk;
            pk.x = (short)f2bf(p0); pk.y = (short)f2bf(p1);
            pk.z = (short)f2bf(p2); pk.w = (short)f2bf(p3);
            *(short4*)(&Pl[w][llo][kb * 16 + lhi * 4]) = pk;
        }
        rsum += __shfl_xor(rsum, 16, 64);
        rsum += __shfl_xor(rsum, 32, 64);
        l_ = l_ * alpha + rsum;
#pragma unroll
        for (int hb = 0; hb < 4; ++hb)
#pragma unroll
            for (int r = 0; r < 4; ++r) o[hb][r] *= alpha;

        __builtin_amdgcn_s_waitcnt(0xC07F);   // lgkmcnt(0): P writes visible (wave-private)

        // O^T += Vt-tile · P : A=Vs[hd][s], B=Pl[q][s]
#pragma unroll
        for (int ks2 = 0; ks2 < 2; ++ks2) {
            bf16x8 pf = *(const bf16x8*)(&Pl[w][llo][ks2 * 32 + lhi * 8]);
            bf16x8 vf[4];
#pragma unroll
            for (int hb = 0; hb < 4; ++hb) vf[hb] = sfrag(Vs, hb * 16 + llo, ks2 * 4 + lhi);
#pragma unroll
            for (int hb = 0; hb < 4; ++hb)
                o[hb] = __builtin_amdgcn_mfma_f32_16x16x32_bf16(
                    vf[hb], pf, o[hb], 0, 0, 0);
        }
    }

    // epilogue: lane q = qt*16+llo, hd = hb*16+lhi*4+r
    u16* Cp = Ctx + (size_t)(b * 2048 + qt * 16) * 2048 + h * 64;
    float inv = 1.0f / l_;
#pragma unroll
    for (int hb = 0; hb < 4; ++hb) {
        short4 v;
        v.x = (short)f2bf(o[hb][0] * inv);
        v.y = (short)f2bf(o[hb][1] * inv);
        v.z = (short)f2bf(o[hb][2] * inv);
        v.w = (short)f2bf(o[hb][3] * inv);
        *(short4*)(Cp + (size_t)llo * 2048 + hb * 16 + lhi * 4) = v;
    }
}

extern "C" void kernel_launch(void* const* d_in, const int* in_sizes, int n_in,
                              void* d_out, int out_size, void* d_ws, size_t ws_size,
                              hipStream_t stream) {
    const float* x  = (const float*)d_in[0];
    const float* Wq = (const float*)d_in[1];
    const float* Wk = (const float*)d_in[2];
    const float* Wv = (const float*)d_in[3];
    const float* Wo = (const float*)d_in[4];

    u16* xb  = (u16*)d_ws;
    u16* wqb = xb + 8388608;
    u16* wkb = wqb + 4194304;
    u16* wvb = wkb + 1048576;
    u16* wob = wvb + 1048576;
    u16* Kb  = wob + 4194304;
    u16* Vtb = Kb + 2097152;
    u16* Ctx = xb;               // overlay (xb dead after projections)
    u16* Qb  = (u16*)d_out;      // bf16 Q staged in fp32 out buffer
    float* out = (float*)d_out;

    cvt_all<<<dim3(9216), 256, 0, stream>>>(x, Wq, Wk, Wv, Wo, xb, wqb, wkb, wvb, wob);
    gemm_qkv<<<dim3(24, 32), 256, 0, stream>>>(xb, wqb, wkb, wvb, Qb, Kb, Vtb);
    attn4<<<dim3(128, 16), 256, 0, stream>>>(Qb, Kb, Vtb, Ctx);
    gemm_bt<<<dim3(16, 32), 256, 0, stream>>>(Ctx, wob, out, 4096, 2048, 2048);
}

// Round 7
// 315.265 us; speedup vs baseline: 2.9975x; 1.0855x over previous
//
#include <hip/hip_runtime.h>
#include <hip/hip_bf16.h>

typedef unsigned short u16;
typedef short bf16x8 __attribute__((ext_vector_type(8)));
typedef float f32x4 __attribute__((ext_vector_type(4)));

#define NEG_BIG (-1e30f)
#define SCL 0.18033688f   // 0.125 * log2(e): Q pre-scaled so scores are in log2 units

__device__ __forceinline__ u16 f2bf(float f) {
    union { float f; unsigned int u; } x; x.f = f;
    unsigned int r = x.u + 0x7fffu + ((x.u >> 16) & 1u);
    return (u16)(r >> 16);
}

__device__ __forceinline__ void dma16(const u16* g, const u16* lds) {
    __builtin_amdgcn_global_load_lds(
        (const __attribute__((address_space(1))) unsigned int*)g,
        (__attribute__((address_space(3))) unsigned int*)lds, 16, 0, 0);
}

__device__ __forceinline__ bf16x8 sfrag(const u16* lds, int row, int kb8) {
    int slot = row * 8 + (kb8 ^ (row & 7));
    return *(const bf16x8*)(lds + slot * 8);
}

// ---------------- fused fp32 -> bf16 convert ----------------
__global__ __launch_bounds__(256) void cvt_all(const float* __restrict__ x,
                                               const float* __restrict__ wq,
                                               const float* __restrict__ wk,
                                               const float* __restrict__ wv,
                                               const float* __restrict__ wo,
                                               u16* __restrict__ xb, u16* __restrict__ wqb,
                                               u16* __restrict__ wkb, u16* __restrict__ wvb,
                                               u16* __restrict__ wob) {
    size_t i = (size_t)blockIdx.x * 256 + threadIdx.x;
    const float* s; u16* d; size_t off;
    if      (i < 1048576) { s = x;  d = xb;  off = i; }
    else if (i < 1572864) { s = wq; d = wqb; off = i - 1048576; }
    else if (i < 1703936) { s = wk; d = wkb; off = i - 1572864; }
    else if (i < 1835008) { s = wv; d = wvb; off = i - 1703936; }
    else                  { s = wo; d = wob; off = i - 1835008; }
    const float* p = s + off * 8;
    float4 a = *(const float4*)p;
    float4 b = *(const float4*)(p + 4);
    bf16x8 r;
    r[0] = (short)f2bf(a.x); r[1] = (short)f2bf(a.y);
    r[2] = (short)f2bf(a.z); r[3] = (short)f2bf(a.w);
    r[4] = (short)f2bf(b.x); r[5] = (short)f2bf(b.y);
    r[6] = (short)f2bf(b.z); r[7] = (short)f2bf(b.w);
    *(bf16x8*)(d + off * 8) = r;
}

// ---------------- bf16 GEMM (m97-style), fp32 output ----------------
__global__ __launch_bounds__(256) void gemm_bt(const u16* __restrict__ A,
                                               const u16* __restrict__ Bt,
                                               float* __restrict__ C,
                                               int M, int N, int K) {
    __shared__ u16 As[8192];
    __shared__ u16 Bs[8192];
    const int t = threadIdx.x;
    const int wave = t >> 6, lane = t & 63;
    const int wm = (wave >> 1) * 64, wn = (wave & 1) * 64;
    const int lhi = lane >> 4, llo = lane & 15;
    const int m0 = blockIdx.y * 128, n0 = blockIdx.x * 128;
    const int wbase = wave * 64;

    f32x4 acc[4][4] = {};
    for (int k0 = 0; k0 < K; k0 += 64) {
        const u16* Ab = A + (size_t)m0 * K + k0;
        const u16* Bb = Bt + (size_t)n0 * K + k0;
#pragma unroll
        for (int i = 0; i < 4; ++i) {
            int s = i * 256 + t;
            int row = s >> 3, gch = (s & 7) ^ (row & 7);
            dma16(Ab + (size_t)row * K + gch * 8, As + (i * 256 + wbase) * 8);
            dma16(Bb + (size_t)row * K + gch * 8, Bs + (i * 256 + wbase) * 8);
        }
        __syncthreads();
#pragma unroll
        for (int ks = 0; ks < 2; ++ks) {
            const int kb = ks * 4 + lhi;
            bf16x8 af[4], bfg[4];
#pragma unroll
            for (int mi = 0; mi < 4; ++mi) af[mi] = sfrag(As, wm + mi * 16 + llo, kb);
#pragma unroll
            for (int ni = 0; ni < 4; ++ni) bfg[ni] = sfrag(Bs, wn + ni * 16 + llo, kb);
#pragma unroll
            for (int mi = 0; mi < 4; ++mi)
#pragma unroll
                for (int ni = 0; ni < 4; ++ni)
                    acc[mi][ni] = __builtin_amdgcn_mfma_f32_16x16x32_bf16(
                        af[mi], bfg[ni], acc[mi][ni], 0, 0, 0);
        }
        __syncthreads();
    }
#pragma unroll
    for (int mi = 0; mi < 4; ++mi)
#pragma unroll
        for (int ni = 0; ni < 4; ++ni)
#pragma unroll
            for (int r = 0; r < 4; ++r) {
                int row = m0 + wm + mi * 16 + lhi * 4 + r;
                int col = n0 + wn + ni * 16 + llo;
                C[(size_t)row * N + col] = acc[mi][ni][r];
            }
}

// ---------------- merged Q/K/V projection ----------------
// bx 0..15: Q [4096][2048] bf16, PRE-SCALED by SCL | bx 16..19: K | bx 20..23: Vt
__global__ __launch_bounds__(256) void gemm_qkv(const u16* __restrict__ A,
                                                const u16* __restrict__ Wq,
                                                const u16* __restrict__ Wk,
                                                const u16* __restrict__ Wv,
                                                u16* __restrict__ Qout,
                                                u16* __restrict__ Kout,
                                                u16* __restrict__ Vtout) {
    const int K = 2048;
    __shared__ u16 As[8192];
    __shared__ u16 Bs[8192];
    const int t = threadIdx.x;
    const int wave = t >> 6, lane = t & 63;
    const int wm = (wave >> 1) * 64, wn = (wave & 1) * 64;
    const int lhi = lane >> 4, llo = lane & 15;
    const int m0 = blockIdx.y * 128;
    const int bx = blockIdx.x;
    const int kind = (bx < 16) ? 0 : (bx < 20 ? 1 : 2);
    const int n0 = (kind == 0) ? bx * 128 : (bx & 3) * 128;
    const u16* Bt = ((kind == 0) ? Wq : (kind == 1) ? Wk : Wv) + (size_t)n0 * K;
    const int wbase = wave * 64;

    f32x4 acc[4][4] = {};
    for (int k0 = 0; k0 < K; k0 += 64) {
        const u16* Ab = A + (size_t)m0 * K + k0;
        const u16* Bb = Bt + k0;
#pragma unroll
        for (int i = 0; i < 4; ++i) {
            int s = i * 256 + t;
            int row = s >> 3, gch = (s & 7) ^ (row & 7);
            dma16(Ab + (size_t)row * K + gch * 8, As + (i * 256 + wbase) * 8);
            dma16(Bb + (size_t)row * K + gch * 8, Bs + (i * 256 + wbase) * 8);
        }
        __syncthreads();
#pragma unroll
        for (int ks = 0; ks < 2; ++ks) {
            const int kb = ks * 4 + lhi;
            bf16x8 af[4], bfg[4];
#pragma unroll
            for (int mi = 0; mi < 4; ++mi) af[mi] = sfrag(As, wm + mi * 16 + llo, kb);
#pragma unroll
            for (int ni = 0; ni < 4; ++ni) bfg[ni] = sfrag(Bs, wn + ni * 16 + llo, kb);
#pragma unroll
            for (int mi = 0; mi < 4; ++mi)
#pragma unroll
                for (int ni = 0; ni < 4; ++ni)
                    acc[mi][ni] = __builtin_amdgcn_mfma_f32_16x16x32_bf16(
                        af[mi], bfg[ni], acc[mi][ni], 0, 0, 0);
        }
        __syncthreads();
    }

    if (kind == 0) {
#pragma unroll
        for (int mi = 0; mi < 4; ++mi)
#pragma unroll
            for (int ni = 0; ni < 4; ++ni)
#pragma unroll
                for (int r = 0; r < 4; ++r) {
                    int row = m0 + wm + mi * 16 + lhi * 4 + r;
                    int col = n0 + wn + ni * 16 + llo;
                    Qout[(size_t)row * 2048 + col] = f2bf(acc[mi][ni][r] * SCL);
                }
    } else if (kind == 1) {
#pragma unroll
        for (int mi = 0; mi < 4; ++mi)
#pragma unroll
            for (int ni = 0; ni < 4; ++ni)
#pragma unroll
                for (int r = 0; r < 4; ++r) {
                    int row = m0 + wm + mi * 16 + lhi * 4 + r;
                    int col = n0 + wn + ni * 16 + llo;
                    Kout[(size_t)row * 512 + col] = f2bf(acc[mi][ni][r]);
                }
    } else {
        // Vt[b][g][hd][s]: off = (col + (row>>11)*512)*2048 + (row&2047)
#pragma unroll
        for (int mi = 0; mi < 4; ++mi)
#pragma unroll
            for (int ni = 0; ni < 4; ++ni) {
                int row = m0 + wm + mi * 16 + lhi * 4;
                int col = n0 + wn + ni * 16 + llo;
                size_t off = ((size_t)col + (size_t)(row >> 11) * 512) * 2048 + (row & 2047);
                short4 v;
                v.x = (short)f2bf(acc[mi][ni][0]);
                v.y = (short)f2bf(acc[mi][ni][1]);
                v.z = (short)f2bf(acc[mi][ni][2]);
                v.w = (short)f2bf(acc[mi][ni][3]);
                *(short4*)(Vtout + off) = v;
            }
    }
}

// ---------------- flash GQA attention v5: paired q-tiles (uniform block length) ----------------
// grid: x in [0,64), y = b*8+g. Block x handles qt = 127-x then qt = x:
// iterations = (floor((127-x)/4)+1) + (floor(x/4)+1) = 33 for every x -> perfect balance.
// 1024 blocks, 6 resident/CU (LDS 25.6KB) -> whole grid co-resident, no tail.
__global__ __launch_bounds__(256, 4) void attn5(const u16* __restrict__ Q,
                                                const u16* __restrict__ Kb,
                                                const u16* __restrict__ Vt,
                                                u16* __restrict__ Ctx) {
    __shared__ u16 Ks[4096];        // 64 k-rows x 8 hd-chunks, swizzled (8KB)
    __shared__ u16 Vs[4096];        // 64 hd-rows x 8 s-chunks, swizzled (8KB)
    __shared__ u16 Pl[4][16][72];   // per-wave P[q][s] (9KB)
    const int bg = blockIdx.y;
    const int b = bg >> 3, g = bg & 7;
    const int t = threadIdx.x, w = t >> 6, lane = t & 63;
    const int lhi = lane >> 4, llo = lane & 15;
    const int h = g * 4 + w;
    const int wbase = w * 64;

    const u16* Kp = Kb + (size_t)(b * 2048) * 512 + g * 64;
    const u16* Vp = Vt + (size_t)bg * 64 * 2048;

#pragma unroll
    for (int ph = 0; ph < 2; ++ph) {
        const int qt = ph ? (int)blockIdx.x : 127 - (int)blockIdx.x;

        // Q B-operand fragments (pre-scaled by SCL at projection time)
        const u16* Qp = Q + ((size_t)(b * 2048 + qt * 16)) * 2048 + h * 64;
        bf16x8 aq[2];
#pragma unroll
        for (int ks = 0; ks < 2; ++ks)
            aq[ks] = *(const bf16x8*)(Qp + (size_t)llo * 2048 + ks * 32 + lhi * 8);

        f32x4 o[4] = {};          // O^T: [hd-tile], lane q=llo, hd=hb*16+lhi*4+r
        float m_ = NEG_BIG, l_ = 0.f;

        const int ktmax = (qt * 16 + 15) >> 6;
        for (int kt = 0; kt <= ktmax; ++kt) {
            __syncthreads();
#pragma unroll
            for (int i = 0; i < 2; ++i) {
                int s = i * 256 + t;
                int row = s >> 3, gch = (s & 7) ^ (row & 7);
                dma16(Kp + (size_t)(kt * 64 + row) * 512 + gch * 8, Ks + (i * 256 + wbase) * 8);
                dma16(Vp + (size_t)row * 2048 + (size_t)kt * 64 + gch * 8, Vs + (i * 256 + wbase) * 8);
            }
            __syncthreads();

            // S^T = K Q^T : st[kb], D[m=k][n=q] (already in log2 units)
            f32x4 st[4] = {};
#pragma unroll
            for (int ks = 0; ks < 2; ++ks) {
                const int kb8 = ks * 4 + lhi;
                bf16x8 kf[4];
#pragma unroll
                for (int kb = 0; kb < 4; ++kb) kf[kb] = sfrag(Ks, kb * 16 + llo, kb8);
#pragma unroll
                for (int kb = 0; kb < 4; ++kb)
                    st[kb] = __builtin_amdgcn_mfma_f32_16x16x32_bf16(
                        kf[kb], aq[ks], st[kb], 0, 0, 0);
            }

            // causal mask (uniform branch: only diagonal tiles pay)
            if (kt * 64 + 63 > qt * 16) {
                int qg = qt * 16 + llo;
#pragma unroll
                for (int kb = 0; kb < 4; ++kb)
#pragma unroll
                    for (int r = 0; r < 4; ++r) {
                        int kg = kt * 64 + kb * 16 + lhi * 4 + r;
                        if (kg > qg) st[kb][r] = NEG_BIG;
                    }
            }

            // per-q max: 16 in-lane fmax + 2 shfl
            float mx = st[0][0];
#pragma unroll
            for (int kb = 0; kb < 4; ++kb)
#pragma unroll
                for (int r = 0; r < 4; ++r) mx = fmaxf(mx, st[kb][r]);
            mx = fmaxf(mx, __shfl_xor(mx, 16, 64));
            mx = fmaxf(mx, __shfl_xor(mx, 32, 64));
            float mn = fmaxf(m_, mx);
            float alpha = exp2f(m_ - mn);
            m_ = mn;
            float rsum = 0.f;

            // p = exp2(s - m); store P[q][s] to wave-private LDS
#pragma unroll
            for (int kb = 0; kb < 4; ++kb) {
                float p0 = exp2f(st[kb][0] - m_);
                float p1 = exp2f(st[kb][1] - m_);
                float p2 = exp2f(st[kb][2] - m_);
                float p3 = exp2f(st[kb][3] - m_);
                rsum += (p0 + p1) + (p2 + p3);
                short4 pk;
                pk.x = (short)f2bf(p0); pk.y = (short)f2bf(p1);
                pk.z = (short)f2bf(p2); pk.w = (short)f2bf(p3);
                *(short4*)(&Pl[w][llo][kb * 16 + lhi * 4]) = pk;
            }
            rsum += __shfl_xor(rsum, 16, 64);
            rsum += __shfl_xor(rsum, 32, 64);
            l_ = l_ * alpha + rsum;
#pragma unroll
            for (int hb = 0; hb < 4; ++hb)
#pragma unroll
                for (int r = 0; r < 4; ++r) o[hb][r] *= alpha;

            __builtin_amdgcn_s_waitcnt(0xC07F);   // lgkmcnt(0): wave-private P visible

            // O^T += Vt-tile · P : A=Vs[hd][s], B=Pl[q][s]
#pragma unroll
            for (int ks2 = 0; ks2 < 2; ++ks2) {
                bf16x8 pf = *(const bf16x8*)(&Pl[w][llo][ks2 * 32 + lhi * 8]);
                bf16x8 vf[4];
#pragma unroll
                for (int hb = 0; hb < 4; ++hb) vf[hb] = sfrag(Vs, hb * 16 + llo, ks2 * 4 + lhi);
#pragma unroll
                for (int hb = 0; hb < 4; ++hb)
                    o[hb] = __builtin_amdgcn_mfma_f32_16x16x32_bf16(
                        vf[hb], pf, o[hb], 0, 0, 0);
            }
        }

        // epilogue: lane q = qt*16+llo, hd = hb*16+lhi*4+r
        u16* Cp = Ctx + (size_t)(b * 2048 + qt * 16) * 2048 + h * 64;
        float inv = 1.0f / l_;
#pragma unroll
        for (int hb = 0; hb < 4; ++hb) {
            short4 v;
            v.x = (short)f2bf(o[hb][0] * inv);
            v.y = (short)f2bf(o[hb][1] * inv);
            v.z = (short)f2bf(o[hb][2] * inv);
            v.w = (short)f2bf(o[hb][3] * inv);
            *(short4*)(Cp + (size_t)llo * 2048 + hb * 16 + lhi * 4) = v;
        }
    }
}

extern "C" void kernel_launch(void* const* d_in, const int* in_sizes, int n_in,
                              void* d_out, int out_size, void* d_ws, size_t ws_size,
                              hipStream_t stream) {
    const float* x  = (const float*)d_in[0];
    const float* Wq = (const float*)d_in[1];
    const float* Wk = (const float*)d_in[2];
    const float* Wv = (const float*)d_in[3];
    const float* Wo = (const float*)d_in[4];

    u16* xb  = (u16*)d_ws;
    u16* wqb = xb + 8388608;
    u16* wkb = wqb + 4194304;
    u16* wvb = wkb + 1048576;
    u16* wob = wvb + 1048576;
    u16* Kb  = wob + 4194304;
    u16* Vtb = Kb + 2097152;
    u16* Ctx = xb;               // overlay (xb dead after projections)
    u16* Qb  = (u16*)d_out;      // bf16 Q staged in fp32 out buffer
    float* out = (float*)d_out;

    cvt_all<<<dim3(9216), 256, 0, stream>>>(x, Wq, Wk, Wv, Wo, xb, wqb, wkb, wvb, wob);
    gemm_qkv<<<dim3(24, 32), 256, 0, stream>>>(xb, wqb, wkb, wvb, Qb, Kb, Vtb);
    attn5<<<dim3(64, 16), 256, 0, stream>>>(Qb, Kb, Vtb, Ctx);
    gemm_bt<<<dim3(16, 32), 256, 0, stream>>>(Ctx, wob, out, 4096, 2048, 2048);
}